// Round 10
// baseline (321.666 us; speedup 1.0000x reference)
//
#include <hip/hip_runtime.h>

typedef __attribute__((ext_vector_type(8))) _Float16 f16x8;
typedef __attribute__((ext_vector_type(16))) float   f32x16;
typedef unsigned int u32;

#define NPTS   65536
#define ROWS   512      // A-rows per block (8 waves x 64 rows each)
#define CH     1024     // B-cols staged in LDS per chunk
#define JSLICE 8192     // B-cols scanned per block
#define NIBLK  128      // 65536 / ROWS
#define NJSP   8        // 65536 / JSLICE

__device__ __forceinline__ u32 umin2(u32 a, u32 b) { return a < b ? a : b; }

// ---------------------------------------------------------------------------
// Packing math (round-3/8-verified on hardware, absmax 0.0):
//  d(a,b) = |a|^2 + |b|^2 - 2 a.b via ONE K=16 f16 MFMA, |a|^2 entering
//  through the MFMA C-operand -> every output is a true squared distance.
//  Q frag: h0:[xh,yh,zh, xl,yl,zl, xh,yh]  h1:[zh, xl,yl,zl, 1,1,1, 0]
//  T frag: h0:[cx,cy,cz, cx,cy,cz, dx,dy]  h1:[dz, dx,dy,dz, q0,q1,q2, 0]
//  c* = -2*high(b), d* = -2*low(b), q0+q1+q2 = |b|^2 (3-term f16 split).
// ---------------------------------------------------------------------------
__device__ __forceinline__ void pack_target_frags(float x, float y, float z,
                                                  f16x8& t0, f16x8& t1)
{
    const _Float16 xh = (_Float16)x, yh = (_Float16)y, zh = (_Float16)z;
    const _Float16 xl = (_Float16)(x - (float)xh);
    const _Float16 yl = (_Float16)(y - (float)yh);
    const _Float16 zl = (_Float16)(z - (float)zh);
    const _Float16 cx = (_Float16)(-2.0f * (float)xh);
    const _Float16 cy = (_Float16)(-2.0f * (float)yh);
    const _Float16 cz = (_Float16)(-2.0f * (float)zh);
    const _Float16 dx = (_Float16)(-2.0f * (float)xl);
    const _Float16 dy = (_Float16)(-2.0f * (float)yl);
    const _Float16 dz = (_Float16)(-2.0f * (float)zl);
    const float sq = fmaf(z, z, fmaf(y, y, x * x));
    const _Float16 q0 = (_Float16)sq;
    const float    r1 = sq - (float)q0;
    const _Float16 q1 = (_Float16)r1;
    const _Float16 q2 = (_Float16)(r1 - (float)q1);
    const f16x8 a = {cx, cy, cz, cx, cy, cz, dx, dy};
    const f16x8 b = {dz, dx, dy, dz, q0, q1, q2, (_Float16)0.0f};
    t0 = a; t1 = b;
}

__device__ __forceinline__ f16x8 pack_query_frag(float x, float y, float z, int half)
{
    const _Float16 xh = (_Float16)x, yh = (_Float16)y, zh = (_Float16)z;
    const _Float16 xl = (_Float16)(x - (float)xh);
    const _Float16 yl = (_Float16)(y - (float)yh);
    const _Float16 zl = (_Float16)(z - (float)zh);
    const _Float16 one = (_Float16)1.0f, zero = (_Float16)0.0f;
    if (half == 0) { const f16x8 v = {xh, yh, zh, xl, yl, zl, xh, yh}; return v; }
    const f16x8 v = {zh, xl, yl, zl, one, one, one, zero}; return v;
}

// ONE pass over the A-rows x B-cols tile grid computing BOTH reductions:
// row-min (A->B) in registers (round-8/9-proven), col-min (B->A) via per-lane
// reg tree + cross-half shuffle + LDS atomicMin + per-chunk global flush.
// All merges in the uint domain (squared distances >= 0 up to ~1e-5
// cancellation whose negative bit patterns map to huge uints -> ignored;
// uint order == float order; umin chains fuse to v_min3_u32).
// NO inline asm anywhere (rounds 4-7: asm touching MFMA data corrupts).
__global__ __launch_bounds__(512, 2) void chamfer_mfma_kernel(
    const float* __restrict__ A, const float* __restrict__ B,
    unsigned int* __restrict__ dmin)
{
    __shared__ _Float16 Al[2 * ROWS * 8];   // 16 KB
    __shared__ float    Aq[ROWS];           // 2 KB
    __shared__ _Float16 Bl[2 * CH * 8];     // 32 KB
    __shared__ u32      Cm[CH];             // 4 KB  (54 KB total -> 2 blk/CU)

    const int bid  = blockIdx.x;            // 0..1023
    const int iblk = bid >> 3;              // 0..127  A-row block
    const int jsp  = bid & 7;               // 0..7    B-col slice

    u32* __restrict__ dmRow = dmin;         // A->B per-row mins
    u32* __restrict__ dmCol = dmin + NPTS;  // B->A per-col mins

    const int t     = threadIdx.x;
    const int lane  = t & 63;
    const int wid   = t >> 6;               // wave owns rows [wid*64, +64)
    const int half  = lane >> 5;
    const int l31   = lane & 31;
    const int ibase = iblk * ROWS;
    const int jbase = jsp * JSLICE;

    // ---- stage A tile: 512 threads -> 512 rows ----
    {
        const float x = A[(ibase + t) * 3 + 0];
        const float y = A[(ibase + t) * 3 + 1];
        const float z = A[(ibase + t) * 3 + 2];
        const f16x8 q0 = pack_query_frag(x, y, z, 0);
        const f16x8 q1 = pack_query_frag(x, y, z, 1);
        *(f16x8*)&Al[t * 8] = q0;
        *(f16x8*)&Al[ROWS * 8 + t * 8] = q1;
        Aq[t] = fmaf(z, z, fmaf(y, y, x * x));
    }
    __syncthreads();

    // A fragments: af0 = rows [wid*64, +32), af1 = rows [wid*64+32, +32)
    const f16x8 af0 = *(const f16x8*)&Al[half * (ROWS * 8) + (wid * 64 + l31) * 8];
    const f16x8 af1 = *(const f16x8*)&Al[half * (ROWS * 8) + (wid * 64 + 32 + l31) * 8];

    // C-operands: |a|^2 broadcast along cols; C/D layout (round-3-verified):
    // col = lane&31, row = (r&3) + 8*(r>>2) + 4*half
    f32x16 cqA, cqB;
#pragma unroll
    for (int r = 0; r < 16; ++r) {
        const int crow = (r & 3) + 8 * (r >> 2) + 4 * half;
        cqA[r] = Aq[wid * 64 + crow];
        cqB[r] = Aq[wid * 64 + 32 + crow];
    }

    u32 rminA[16], rminB[16];
#pragma unroll
    for (int i = 0; i < 16; ++i) { rminA[i] = 0x7F7F7F7Fu; rminB[i] = 0x7F7F7F7Fu; }

    for (int ch = 0; ch < JSLICE / CH; ++ch) {
        __syncthreads();
        // ---- pack B chunk (2 cols/thread) + init col-min array ----
#pragma unroll
        for (int pp = 0; pp < 2; ++pp) {
            const int c = t + pp * 512;
            const int g = jbase + ch * CH + c;
            f16x8 t0, t1;
            pack_target_frags(B[g * 3 + 0], B[g * 3 + 1], B[g * 3 + 2], t0, t1);
            *(f16x8*)&Bl[c * 8] = t0;
            *(f16x8*)&Bl[CH * 8 + c * 8] = t1;
            Cm[c] = 0x7F7F7F7Fu;
        }
        __syncthreads();

#pragma unroll 2
        for (int jt = 0; jt < CH / 32; jt += 2) {
            const f16x8 bf0 = *(const f16x8*)&Bl[half * (CH * 8) + (jt * 32 + l31) * 8];
            const f16x8 bf1 = *(const f16x8*)&Bl[half * (CH * 8) + ((jt + 1) * 32 + l31) * 8];
            const f32x16 d00 = __builtin_amdgcn_mfma_f32_32x32x16_f16(af0, bf0, cqA, 0, 0, 0);
            const f32x16 d01 = __builtin_amdgcn_mfma_f32_32x32x16_f16(af0, bf1, cqA, 0, 0, 0);
            const f32x16 d10 = __builtin_amdgcn_mfma_f32_32x32x16_f16(af1, bf0, cqB, 0, 0, 0);
            const f32x16 d11 = __builtin_amdgcn_mfma_f32_32x32x16_f16(af1, bf1, cqB, 0, 0, 0);

            u32 c0 = 0x7F7F7F7Fu, c1 = 0x7F7F7F7Fu;
#pragma unroll
            for (int r = 0; r < 16; ++r) {
                const u32 a0 = __float_as_uint(d00[r]);
                const u32 a1 = __float_as_uint(d01[r]);
                const u32 b0 = __float_as_uint(d10[r]);
                const u32 b1 = __float_as_uint(d11[r]);
                rminA[r] = umin2(rminA[r], umin2(a0, a1));   // rows wid*64..+31
                rminB[r] = umin2(rminB[r], umin2(b0, b1));   // rows wid*64+32..+63
                c0 = umin2(c0, umin2(a0, b0));               // cols of bf0
                c1 = umin2(c1, umin2(a1, b1));               // cols of bf1
            }
            // cross-half: lane l and l^32 hold the same col, different rows
            c0 = umin2(c0, (u32)__shfl_xor((int)c0, 32, 64));
            c1 = umin2(c1, (u32)__shfl_xor((int)c1, 32, 64));
            if (half == 0) {
                atomicMin(&Cm[jt * 32 + l31], c0);
                atomicMin(&Cm[(jt + 1) * 32 + l31], c1);
            }
        }
        __syncthreads();
        // ---- flush this chunk's col-mins to global ----
#pragma unroll
        for (int pp = 0; pp < 2; ++pp) {
            const int c = t + pp * 512;
            atomicMin(&dmCol[jbase + ch * CH + c], Cm[c]);
        }
    }

    // ---- row epilogue: min over 32 col-residues (lane bits 0..4) ----
#pragma unroll
    for (int m = 1; m <= 16; m <<= 1) {
#pragma unroll
        for (int r = 0; r < 16; ++r) {
            rminA[r] = umin2(rminA[r], (u32)__shfl_xor((int)rminA[r], m, 64));
            rminB[r] = umin2(rminB[r], (u32)__shfl_xor((int)rminB[r], m, 64));
        }
    }
    if (l31 == 0) {
#pragma unroll
        for (int r = 0; r < 16; ++r) {
            const int crow = (r & 3) + 8 * (r >> 2) + 4 * half;
            atomicMin(&dmRow[ibase + wid * 64 + crow], rminA[r]);
            atomicMin(&dmRow[ibase + wid * 64 + 32 + crow], rminB[r]);
        }
    }
}

// Sum dmin over all 2*65536 entries; out += blockSum / 65536.
__global__ __launch_bounds__(256) void chamfer_reduce_kernel(
    const unsigned int* __restrict__ dmin, float* __restrict__ out)
{
    const int i = blockIdx.x * 256 + threadIdx.x;
    float v = __uint_as_float(dmin[i]);
#pragma unroll
    for (int off = 32; off > 0; off >>= 1)
        v += __shfl_down(v, off, 64);
    __shared__ float ws2[4];
    const int lane = threadIdx.x & 63;
    const int wid  = threadIdx.x >> 6;
    if (lane == 0) ws2[wid] = v;
    __syncthreads();
    if (threadIdx.x == 0)
        atomicAdd(out, (ws2[0] + ws2[1] + ws2[2] + ws2[3]) * (1.0f / (float)NPTS));
}

// ============================================================================
extern "C" void kernel_launch(void* const* d_in, const int* in_sizes, int n_in,
                              void* d_out, int out_size, void* d_ws, size_t ws_size,
                              hipStream_t stream)
{
    const float* A = (const float*)d_in[0];   // pc0 (65536,3) f32
    const float* B = (const float*)d_in[1];   // pc1 (65536,3) f32
    float* out = (float*)d_out;               // scalar f32
    unsigned int* dmin = (unsigned int*)d_ws; // 512 KB, proven sufficient r2/r3

    hipMemsetAsync(dmin, 0x7F, 2 * NPTS * sizeof(unsigned int), stream);
    hipMemsetAsync(out, 0, sizeof(float), stream);

    chamfer_mfma_kernel<<<NIBLK * NJSP, 512, 0, stream>>>(A, B, dmin);
    chamfer_reduce_kernel<<<(2 * NPTS) / 256, 256, 0, stream>>>(dmin, out);
}